// Round 9
// baseline (182.138 us; speedup 1.0000x reference)
//
#include <hip/hip_runtime.h>

#define N_IN   16384
#define N_OUT  16384
#define KSZ    9
#define CIN    32
#define COUT   32
#define BC     64
#define NBUCK  1024        // k_bin bucket = io >> 4  (16 n per bucket)
#define CHUNK  2048
#define ECAP   2048        // siv region per bucket
#define ROWS_L 72          // rows per half-bucket: 9 k * 8 n
#define XSTR   68          // LDS xk row stride: %32==4 -> 4-way max on b128, 16B-aligned
#define SCAP   1024        // slist cap per half-bucket (mean 732, +10 sigma)

// ---------------------------------------------------------------------------
// blocks 0..255: xq[in][bc] = x[bc][in] * qw[in]; block 256: wT transpose + gcnt zero
__global__ void k_xq(const float* __restrict__ x, const float* __restrict__ qw,
                     float* __restrict__ xq, const float* __restrict__ w,
                     float* __restrict__ wT, int* __restrict__ gcnt) {
    const int tid = threadIdx.x;
    if (blockIdx.x == 256) {
        for (int i = tid; i < COUT * CIN * KSZ; i += 256) {
            int o = i / (CIN * KSZ);
            int r = i - o * (CIN * KSZ);
            int c = r / KSZ;
            int k = r - c * KSZ;
            wT[((k * 8 + (o >> 2)) * 32 + c) * 4 + (o & 3)] = w[i];
        }
        for (int i = tid; i < NBUCK; i += 256) gcnt[i] = 0;
        return;
    }
    __shared__ float tile[64 * 65];
    const int in0 = blockIdx.x * 64;
#pragma unroll
    for (int i = 0; i < 16; ++i) {
        int idx = tid + i * 256;
        int bcl = idx >> 6, inl = idx & 63;
        tile[bcl * 65 + inl] = x[bcl * N_IN + in0 + inl];
    }
    __syncthreads();
#pragma unroll
    for (int i = 0; i < 16; ++i) {
        int idx = tid + i * 256;
        int inl = idx >> 6, bcl = idx & 63;
        xq[(size_t)(in0 + inl) * BC + bcl] = tile[bcl * 65 + inl] * qw[in0 + inl];
    }
}

// ---------------------------------------------------------------------------
// binning with block-local counting sort -> coalesced run flush.
// payload = (bucket<<22) | (in<<8) | row ; row = k*16 + (io&15).
__global__ __launch_bounds__(512) void k_bin(const float* __restrict__ vals,
        const int* __restrict__ ik, const int* __restrict__ io, const int* __restrict__ ii,
        int* __restrict__ gcnt, float2* __restrict__ siv, int nnz) {
    __shared__ int    cnt[NBUCK];      // counts, then exclusive localStart
    __shared__ int    gbase[NBUCK];
    __shared__ int    cursor[NBUCK];
    __shared__ float2 slist[CHUNK];    // 16 KB
    const int t = threadIdx.x, c = blockIdx.x;
    cnt[t] = 0; cnt[t + 512] = 0;
    __syncthreads();
    const int base = c * CHUNK;
    const int e0   = base + t * 4;

    float vv[4]; int pk[4]; int bk[4]; bool hv[4];
    if (e0 + 4 <= nnz) {
        int4   a = *(const int4*)(io + e0);
        int4   b = *(const int4*)(ii + e0);
        int4   k = *(const int4*)(ik + e0);
        float4 d = *(const float4*)(vals + e0);
        int ov[4] = {a.x, a.y, a.z, a.w};
        int iv[4] = {b.x, b.y, b.z, b.w};
        int kv[4] = {k.x, k.y, k.z, k.w};
        float dv[4] = {d.x, d.y, d.z, d.w};
#pragma unroll
        for (int j = 0; j < 4; ++j) {
            hv[j] = true;
            bk[j] = ov[j] >> 4;
            pk[j] = (bk[j] << 22) | (iv[j] << 8) | (kv[j] * 16 + (ov[j] & 15));
            vv[j] = dv[j];
        }
    } else {
#pragma unroll
        for (int j = 0; j < 4; ++j) {
            int e = e0 + j;
            hv[j] = (e < nnz);
            if (hv[j]) {
                int o = io[e];
                bk[j] = o >> 4;
                pk[j] = (bk[j] << 22) | (ii[e] << 8) | (ik[e] * 16 + (o & 15));
                vv[j] = vals[e];
            } else { bk[j] = 0; pk[j] = 0; vv[j] = 0.f; }
        }
    }
#pragma unroll
    for (int j = 0; j < 4; ++j) if (hv[j]) atomicAdd(&cnt[bk[j]], 1);
    __syncthreads();
    // ---- global run reservation
    {
        int b0 = t, b1 = t + 512;
        int c0 = cnt[b0], c1 = cnt[b1];
        int g0 = c0 ? atomicAdd(&gcnt[b0], c0) : 0;
        int g1 = c1 ? atomicAdd(&gcnt[b1], c1) : 0;
        gbase[b0] = b0 * ECAP + g0;
        gbase[b1] = b1 * ECAP + g1;
    }
    __syncthreads();
    // ---- wave-0 in-place exclusive scan of cnt over 1024
    if (t < 64) {
        int carry = 0;
#pragma unroll
        for (int seg = 0; seg < 16; ++seg) {
            int idx = seg * 64 + t;
            int v = cnt[idx];
            int orig = v;
#pragma unroll
            for (int off = 1; off < 64; off <<= 1) {
                int u = __shfl_up(v, off);
                if (t >= off) v += u;
            }
            cnt[idx] = carry + v - orig;
            carry += __shfl(v, 63);
        }
    }
    __syncthreads();
    cursor[t] = cnt[t]; cursor[t + 512] = cnt[t + 512];
    __syncthreads();
#pragma unroll
    for (int j = 0; j < 4; ++j) {
        if (hv[j]) {
            int pos = atomicAdd(&cursor[bk[j]], 1);
            slist[pos] = make_float2(vv[j], __int_as_float(pk[j]));
        }
    }
    __syncthreads();
    // ---- coalesced flush: consecutive p -> consecutive dest within runs
    const int m = min(nnz - base, CHUNK);
    for (int p = t; p < m; p += 512) {
        float2 f = slist[p];
        int b = (int)((unsigned)__float_as_int(f.y) >> 22);
        int dest = gbase[b] + (p - cnt[b]);
        if (dest < ((b + 1) << 11)) siv[dest] = f;   // ECAP = 1<<11
    }
}

// ---------------------------------------------------------------------------
// fused: block = half-bucket (8 n). Reads the full bucket's entries, sorts its
// half's rows (72) into LDS, per-wave register accumulation, einsum.
__global__ __launch_bounds__(512) void k_fused4(const float* __restrict__ xq,
        const float2* __restrict__ siv, const int* __restrict__ gcnt,
        const float* __restrict__ wT, const float* __restrict__ bias,
        float* __restrict__ out) {
    __shared__ float  sxk[ROWS_L * XSTR];  // 19584 B
    __shared__ float2 slist[SCAP];         // 8192 B
    __shared__ int    rowStart[ROWS_L + 1];
    __shared__ int    cursor[ROWS_L];
    const int tid  = threadIdx.x;
    const int lane = tid & 63;
    const int wv   = __builtin_amdgcn_readfirstlane(tid >> 6);
    const int bkt  = blockIdx.x >> 1;
    const int half = blockIdx.x & 1;

    for (int i = tid; i < ROWS_L * XSTR; i += 512) sxk[i] = 0.f;
    if (tid < ROWS_L) rowStart[tid] = 0;
    __syncthreads();

    const int m = min(gcnt[bkt], ECAP);
    const float2* src = siv + (size_t)bkt * ECAP;
    float2 ent[4]; bool ok[4];
#pragma unroll
    for (int j = 0; j < 4; ++j) {
        int i = tid + j * 512;
        bool inr = (i < m);
        ok[j] = false;
        if (inr) {
            ent[j] = src[i];
            int row = __float_as_int(ent[j].y) & 0xFF;
            if (((row >> 3) & 1) == half) {
                ok[j] = true;
                int rl = (row >> 4) * 8 + (row & 7);
                atomicAdd(&rowStart[rl], 1);
            }
        }
    }
    __syncthreads();
    // ---- wave-0 exclusive scan over 72 counts
    if (wv == 0) {
        int carry = 0;
#pragma unroll
        for (int i0 = 0; i0 < 128; i0 += 64) {
            int idx = i0 + lane;
            int v = (idx < ROWS_L) ? rowStart[idx] : 0;
            int orig = v;
#pragma unroll
            for (int off = 1; off < 64; off <<= 1) {
                int u = __shfl_up(v, off);
                if (lane >= off) v += u;
            }
            if (idx < ROWS_L) {
                int excl = carry + v - orig;
                rowStart[idx] = excl;
                cursor[idx]   = excl;
            }
            carry += __shfl(v, 63);
        }
        if (lane == 0) rowStart[ROWS_L] = carry;
    }
    __syncthreads();
#pragma unroll
    for (int j = 0; j < 4; ++j) {
        if (ok[j]) {
            int row = __float_as_int(ent[j].y) & 0xFF;
            int rl  = (row >> 4) * 8 + (row & 7);
            int pos = atomicAdd(&cursor[rl], 1);
            if (pos < SCAP) slist[pos] = ent[j];
        }
    }
    __syncthreads();
    // ---- per-wave row accumulation: 32-bit byte-offset gathers, 8-deep
    const char* xqb   = (const char*)xq;
    const int   lane4 = lane * 4;
    for (int r = wv; r < ROWS_L; r += 8) {
        const int a = rowStart[r], b = min(rowStart[r + 1], SCAP);
        if (a >= b) continue;
        float acc0 = 0.f, acc1 = 0.f, acc2 = 0.f, acc3 = 0.f;
        int i = a;
        for (; i + 7 < b; i += 8) {
            float2 v0 = slist[i],     v1 = slist[i + 1], v2 = slist[i + 2], v3 = slist[i + 3];
            float2 v4 = slist[i + 4], v5 = slist[i + 5], v6 = slist[i + 6], v7 = slist[i + 7];
            acc0 += *(const float*)(xqb + ((__float_as_int(v0.y) & 0x3FFF00) + lane4)) * v0.x;
            acc1 += *(const float*)(xqb + ((__float_as_int(v1.y) & 0x3FFF00) + lane4)) * v1.x;
            acc2 += *(const float*)(xqb + ((__float_as_int(v2.y) & 0x3FFF00) + lane4)) * v2.x;
            acc3 += *(const float*)(xqb + ((__float_as_int(v3.y) & 0x3FFF00) + lane4)) * v3.x;
            acc0 += *(const float*)(xqb + ((__float_as_int(v4.y) & 0x3FFF00) + lane4)) * v4.x;
            acc1 += *(const float*)(xqb + ((__float_as_int(v5.y) & 0x3FFF00) + lane4)) * v5.x;
            acc2 += *(const float*)(xqb + ((__float_as_int(v6.y) & 0x3FFF00) + lane4)) * v6.x;
            acc3 += *(const float*)(xqb + ((__float_as_int(v7.y) & 0x3FFF00) + lane4)) * v7.x;
        }
        for (; i + 3 < b; i += 4) {
            float2 v0 = slist[i], v1 = slist[i + 1], v2 = slist[i + 2], v3 = slist[i + 3];
            acc0 += *(const float*)(xqb + ((__float_as_int(v0.y) & 0x3FFF00) + lane4)) * v0.x;
            acc1 += *(const float*)(xqb + ((__float_as_int(v1.y) & 0x3FFF00) + lane4)) * v1.x;
            acc2 += *(const float*)(xqb + ((__float_as_int(v2.y) & 0x3FFF00) + lane4)) * v2.x;
            acc3 += *(const float*)(xqb + ((__float_as_int(v3.y) & 0x3FFF00) + lane4)) * v3.x;
        }
        for (; i < b; ++i) {
            float2 v = slist[i];
            acc0 += *(const float*)(xqb + ((__float_as_int(v.y) & 0x3FFF00) + lane4)) * v.x;
        }
        sxk[r * XSTR + lane] = (acc0 + acc1) + (acc2 + acc3);
    }
    __syncthreads();

    // ---- einsum (lanes 0..15): out[h][o][n0+nl] = sum_{k,c} sxk[k*8+nl][h*32+c]*w
    if (lane < 16) {
        const int h  = lane >> 3;
        const int nl = lane & 7;
        const int n0 = blockIdx.x * 8;
        float acc[4] = {0.f, 0.f, 0.f, 0.f};
        for (int k = 0; k < KSZ; ++k) {
            const float* xr = &sxk[(k * 8 + nl) * XSTR + h * 32];
            const float* wp = &wT[(k * 8 + wv) * 128];          // wave-uniform -> s_load
#pragma unroll
            for (int c4 = 0; c4 < 8; ++c4) {
                float4 xv = *(const float4*)&xr[c4 * 4];
#pragma unroll
                for (int cc = 0; cc < 4; ++cc) {
                    float xval = (&xv.x)[cc];
#pragma unroll
                    for (int j = 0; j < 4; ++j)
                        acc[j] += xval * wp[(c4 * 4 + cc) * 4 + j];
                }
            }
        }
#pragma unroll
        for (int j = 0; j < 4; ++j) {
            int o = wv * 4 + j;
            out[((size_t)h * COUT + o) * N_OUT + n0 + nl] = acc[j] + bias[o];
        }
    }
}

// ---------------------------------------------------------------------------
extern "C" void kernel_launch(void* const* d_in, const int* in_sizes, int n_in,
                              void* d_out, int out_size, void* d_ws, size_t ws_size,
                              hipStream_t stream) {
    const float* x    = (const float*)d_in[0];
    const float* qw   = (const float*)d_in[1];
    const float* vals = (const float*)d_in[2];
    const float* w    = (const float*)d_in[3];
    const float* bias = (const float*)d_in[4];
    const int*   ik   = (const int*)d_in[5];
    const int*   io   = (const int*)d_in[6];
    const int*   ii   = (const int*)d_in[7];
    const int    nnz  = in_sizes[2];
    const int    nch  = (nnz + CHUNK - 1) / CHUNK;

    char* ws = (char*)d_ws;
    float*  xq   = (float*)ws;  ws += (size_t)N_IN * BC * 4;          // 4 MB
    float2* siv  = (float2*)ws; ws += (size_t)NBUCK * ECAP * 8;       // 16.78 MB
    int*    gcnt = (int*)ws;    ws += (size_t)NBUCK * 4;
    float*  wT   = (float*)ws;  ws += (size_t)COUT * CIN * KSZ * 4;

    k_xq    <<<257, 256, 0, stream>>>(x, qw, xq, w, wT, gcnt);
    k_bin   <<<nch, 512, 0, stream>>>(vals, ik, io, ii, gcnt, siv, nnz);
    k_fused4<<<NBUCK * 2, 512, 0, stream>>>(xq, siv, gcnt, wT, bias, (float*)d_out);
}

// Round 10
// 156.518 us; speedup vs baseline: 1.1637x; 1.1637x over previous
//
#include <hip/hip_runtime.h>

#define N_IN   16384
#define N_OUT  16384
#define KSZ    9
#define CIN    32
#define COUT   32
#define BC     64
#define ROWS   144         // 9 k * 16 n per fine bucket
#define XSTR   68          // LDS xk row stride: %32==4 -> max 4-way on b128, 16B-aligned
#define CHA    4096        // pass-A chunk
#define ECAP_A 32768       // sivA region per coarse bucket (mean 23437)
#define ECAP_B 2048        // sivB region per fine bucket (mean 1465)

// ---------------------------------------------------------------------------
// blocks 0..255: xq[in][bc] = x[bc][in]*qw[in]; block 256: wT transpose + cnt zero
__global__ void k_xq(const float* __restrict__ x, const float* __restrict__ qw,
                     float* __restrict__ xq, const float* __restrict__ w,
                     float* __restrict__ wT, int* __restrict__ gcntA,
                     int* __restrict__ gcntB) {
    const int tid = threadIdx.x;
    if (blockIdx.x == 256) {
        for (int i = tid; i < COUT * CIN * KSZ; i += 256) {
            int o = i / (CIN * KSZ);
            int r = i - o * (CIN * KSZ);
            int c = r / KSZ;
            int k = r - c * KSZ;
            wT[((k * 8 + (o >> 2)) * 32 + c) * 4 + (o & 3)] = w[i];
        }
        for (int i = tid; i < 1024; i += 256) gcntB[i] = 0;
        if (tid < 64) gcntA[tid] = 0;
        return;
    }
    __shared__ float tile[64 * 65];
    const int in0 = blockIdx.x * 64;
#pragma unroll
    for (int i = 0; i < 16; ++i) {
        int idx = tid + i * 256;
        int bcl = idx >> 6, inl = idx & 63;
        tile[bcl * 65 + inl] = x[bcl * N_IN + in0 + inl];
    }
    __syncthreads();
#pragma unroll
    for (int i = 0; i < 16; ++i) {
        int idx = tid + i * 256;
        int inl = idx >> 6, bcl = idx & 63;
        xq[(size_t)(in0 + inl) * BC + bcl] = tile[bcl * 65 + inl] * qw[in0 + inl];
    }
}

// ---------------------------------------------------------------------------
// pass A: bin into 64 coarse buckets (io>>8). Runs ~64 entries = 512B.
// payload = (io>>4)<<22 | in<<8 | row ; row = k*16 + (io&15).
__global__ __launch_bounds__(512) void k_binA(const float* __restrict__ vals,
        const int* __restrict__ ik, const int* __restrict__ io, const int* __restrict__ ii,
        int* __restrict__ gcntA, float2* __restrict__ sivA, int nnz) {
    __shared__ int    cntE[64];      // exclusive local start
    __shared__ int    gbase[64];
    __shared__ int    cursor[64];
    __shared__ int    cnt[64];
    __shared__ float2 slist[CHA];    // 32 KB
    const int t = threadIdx.x, c = blockIdx.x;
    if (t < 64) cnt[t] = 0;
    __syncthreads();
    const int base = c * CHA;
    const int e0   = base + t * 8;

    float vv[8]; int pk[8]; int bk[8]; bool hv[8];
    if (e0 + 8 <= nnz) {
        int4 a0 = *(const int4*)(io + e0),  a1 = *(const int4*)(io + e0 + 4);
        int4 b0 = *(const int4*)(ii + e0),  b1 = *(const int4*)(ii + e0 + 4);
        int4 k0 = *(const int4*)(ik + e0),  k1 = *(const int4*)(ik + e0 + 4);
        float4 d0 = *(const float4*)(vals + e0), d1 = *(const float4*)(vals + e0 + 4);
        int ov[8] = {a0.x, a0.y, a0.z, a0.w, a1.x, a1.y, a1.z, a1.w};
        int iv[8] = {b0.x, b0.y, b0.z, b0.w, b1.x, b1.y, b1.z, b1.w};
        int kv[8] = {k0.x, k0.y, k0.z, k0.w, k1.x, k1.y, k1.z, k1.w};
        float dv[8] = {d0.x, d0.y, d0.z, d0.w, d1.x, d1.y, d1.z, d1.w};
#pragma unroll
        for (int j = 0; j < 8; ++j) {
            hv[j] = true;
            bk[j] = ov[j] >> 8;
            pk[j] = ((ov[j] >> 4) << 22) | (iv[j] << 8) | (kv[j] * 16 + (ov[j] & 15));
            vv[j] = dv[j];
        }
    } else {
#pragma unroll
        for (int j = 0; j < 8; ++j) {
            int e = e0 + j;
            hv[j] = (e < nnz);
            if (hv[j]) {
                int o = io[e];
                bk[j] = o >> 8;
                pk[j] = ((o >> 4) << 22) | (ii[e] << 8) | (ik[e] * 16 + (o & 15));
                vv[j] = vals[e];
            } else { bk[j] = 0; pk[j] = 0; vv[j] = 0.f; }
        }
    }
#pragma unroll
    for (int j = 0; j < 8; ++j) if (hv[j]) atomicAdd(&cnt[bk[j]], 1);
    __syncthreads();
    // ---- reserve + scan (wave 0, register-resident)
    if (t < 64) {
        int cv = cnt[t];
        gbase[t] = t * ECAP_A + (cv ? atomicAdd(&gcntA[t], cv) : 0);
        int v = cv;
#pragma unroll
        for (int off = 1; off < 64; off <<= 1) {
            int u = __shfl_up(v, off);
            if (t >= off) v += u;
        }
        cntE[t]   = v - cv;
        cursor[t] = v - cv;
    }
    __syncthreads();
#pragma unroll
    for (int j = 0; j < 8; ++j) {
        if (hv[j]) {
            int pos = atomicAdd(&cursor[bk[j]], 1);
            slist[pos] = make_float2(vv[j], __int_as_float(pk[j]));
        }
    }
    __syncthreads();
    const int m = min(nnz - base, CHA);
    for (int p = t; p < m; p += 512) {
        float2 f = slist[p];
        int cb = (int)((unsigned)__float_as_int(f.y) >> 26);
        int dest = gbase[cb] + (p - cntE[cb]);
        if (dest < (cb + 1) * ECAP_A) sivA[dest] = f;
    }
}

// ---------------------------------------------------------------------------
// pass B: 4 blocks per coarse bucket; each streams its quarter in 2048-chunks
// into 16 fine buckets. Runs ~128 entries = 1KB.
__global__ __launch_bounds__(512) void k_binB(const float2* __restrict__ sivA,
        const int* __restrict__ gcntA, int* __restrict__ gcntB,
        float2* __restrict__ sivB) {
    __shared__ float2 slist[2048];   // 16 KB
    __shared__ int cnt16[16], gb16[16], cur16[16];
    const int t  = threadIdx.x;
    const int cb = blockIdx.x >> 2;
    const int q  = blockIdx.x & 3;
    const int mA = min(gcntA[cb], ECAP_A);
    const int q0 = (mA * q) >> 2;
    const int q1 = (mA * (q + 1)) >> 2;
    const float2* src = sivA + (size_t)cb * ECAP_A;

    for (int start = q0; start < q1; start += 2048) {
        const int cm = min(2048, q1 - start);
        if (t < 16) cnt16[t] = 0;
        __syncthreads();
        float2 ent[4]; bool hv[4];
#pragma unroll
        for (int j = 0; j < 4; ++j) {
            int i = start + t + j * 512;
            hv[j] = (i < start + cm);
            if (hv[j]) {
                ent[j] = src[i];
                atomicAdd(&cnt16[((unsigned)__float_as_int(ent[j].y) >> 22) & 15], 1);
            }
        }
        __syncthreads();
        if (t < 16) {
            int cv = cnt16[t];
            int fg = (cb << 4) + t;
            gb16[t] = fg * ECAP_B + (cv ? atomicAdd(&gcntB[fg], cv) : 0);
            int v = cv;
#pragma unroll
            for (int off = 1; off < 16; off <<= 1) {
                int u = __shfl_up(v, off);
                if (t >= off) v += u;
            }
            cnt16[t] = v - cv;
            cur16[t] = v - cv;
        }
        __syncthreads();
#pragma unroll
        for (int j = 0; j < 4; ++j) {
            if (hv[j]) {
                int pos = atomicAdd(&cur16[((unsigned)__float_as_int(ent[j].y) >> 22) & 15], 1);
                slist[pos] = ent[j];
            }
        }
        __syncthreads();
        for (int p = t; p < cm; p += 512) {
            float2 f = slist[p];
            unsigned fg = (unsigned)__float_as_int(f.y) >> 22;
            int fl = fg & 15;
            int dest = gb16[fl] + (p - cnt16[fl]);
            if (dest < (int)((fg + 1) * ECAP_B)) sivB[dest] = f;
        }
        __syncthreads();
    }
}

// ---------------------------------------------------------------------------
// fused: per fine bucket (16 n): load entries to regs, counting-sort by row
// into LDS, then two k-phases (5+4): register accumulation + partial einsum.
// sxk only 80 rows -> LDS ~39 KB -> 4 blocks/CU.
__global__ __launch_bounds__(512) void k_fused5(const float* __restrict__ xq,
        const float2* __restrict__ sivB, const int* __restrict__ gcntB,
        const float* __restrict__ wT, const float* __restrict__ bias,
        float* __restrict__ out) {
    __shared__ float  sxk[80 * XSTR];      // 21760 B
    __shared__ float2 slist[ECAP_B];       // 16384 B
    __shared__ int    rowStart[ROWS + 1];
    __shared__ int    cursor[ROWS];
    const int tid  = threadIdx.x;
    const int lane = tid & 63;
    const int wv   = __builtin_amdgcn_readfirstlane(tid >> 6);
    const int bkt  = blockIdx.x;

    if (tid < ROWS) rowStart[tid] = 0;
    __syncthreads();

    const int m = min(gcntB[bkt], ECAP_B);
    const float2* src = sivB + (size_t)bkt * ECAP_B;
    float2 ent[4]; bool have[4];
#pragma unroll
    for (int j = 0; j < 4; ++j) {
        int i = tid + j * 512;
        have[j] = (i < m);
        if (have[j]) {
            ent[j] = src[i];
            atomicAdd(&rowStart[__float_as_int(ent[j].y) & 0xFF], 1);
        }
    }
    __syncthreads();
    if (wv == 0) {   // exclusive scan over 144 counts
        int carry = 0;
#pragma unroll
        for (int i0 = 0; i0 < 192; i0 += 64) {
            int idx = i0 + lane;
            int v = (idx < ROWS) ? rowStart[idx] : 0;
            int orig = v;
#pragma unroll
            for (int off = 1; off < 64; off <<= 1) {
                int u = __shfl_up(v, off);
                if (lane >= off) v += u;
            }
            if (idx < ROWS) {
                int excl = carry + v - orig;
                rowStart[idx] = excl;
                cursor[idx]   = excl;
            }
            carry += __shfl(v, 63);
        }
        if (lane == 0) rowStart[ROWS] = m;
    }
    __syncthreads();
#pragma unroll
    for (int j = 0; j < 4; ++j) {
        if (have[j]) {
            int pos = atomicAdd(&cursor[__float_as_int(ent[j].y) & 0xFF], 1);
            slist[pos] = ent[j];
        }
    }

    const char* xqb   = (const char*)xq;
    const int   lane4 = lane * 4;
    const int   h     = lane >> 4;       // einsum: lanes<32 -> h in {0,1}
    const int   nl    = lane & 15;
    float acc[4] = {0.f, 0.f, 0.f, 0.f};

#pragma unroll
    for (int ph = 0; ph < 2; ++ph) {
        const int rbase = ph ? 80 : 0;
        const int rend  = ph ? 144 : 80;
        const int nrows = rend - rbase;
        // zero this phase's sxk region (covers rows with no entries)
        for (int i = tid; i < nrows * XSTR; i += 512) sxk[i] = 0.f;
        __syncthreads();   // also covers scatter completion (ph 0)
        // ---- per-wave row accumulation: 32-bit byte-offset gathers, 8-deep
        for (int r = rbase + wv; r < rend; r += 8) {
            const int a = rowStart[r], b = rowStart[r + 1];
            if (a >= b) continue;
            float acc0 = 0.f, acc1 = 0.f, acc2 = 0.f, acc3 = 0.f;
            int i = a;
            for (; i + 7 < b; i += 8) {
                float2 v0 = slist[i],     v1 = slist[i + 1], v2 = slist[i + 2], v3 = slist[i + 3];
                float2 v4 = slist[i + 4], v5 = slist[i + 5], v6 = slist[i + 6], v7 = slist[i + 7];
                acc0 += *(const float*)(xqb + ((__float_as_int(v0.y) & 0x3FFF00) + lane4)) * v0.x;
                acc1 += *(const float*)(xqb + ((__float_as_int(v1.y) & 0x3FFF00) + lane4)) * v1.x;
                acc2 += *(const float*)(xqb + ((__float_as_int(v2.y) & 0x3FFF00) + lane4)) * v2.x;
                acc3 += *(const float*)(xqb + ((__float_as_int(v3.y) & 0x3FFF00) + lane4)) * v3.x;
                acc0 += *(const float*)(xqb + ((__float_as_int(v4.y) & 0x3FFF00) + lane4)) * v4.x;
                acc1 += *(const float*)(xqb + ((__float_as_int(v5.y) & 0x3FFF00) + lane4)) * v5.x;
                acc2 += *(const float*)(xqb + ((__float_as_int(v6.y) & 0x3FFF00) + lane4)) * v6.x;
                acc3 += *(const float*)(xqb + ((__float_as_int(v7.y) & 0x3FFF00) + lane4)) * v7.x;
            }
            for (; i + 3 < b; i += 4) {
                float2 v0 = slist[i], v1 = slist[i + 1], v2 = slist[i + 2], v3 = slist[i + 3];
                acc0 += *(const float*)(xqb + ((__float_as_int(v0.y) & 0x3FFF00) + lane4)) * v0.x;
                acc1 += *(const float*)(xqb + ((__float_as_int(v1.y) & 0x3FFF00) + lane4)) * v1.x;
                acc2 += *(const float*)(xqb + ((__float_as_int(v2.y) & 0x3FFF00) + lane4)) * v2.x;
                acc3 += *(const float*)(xqb + ((__float_as_int(v3.y) & 0x3FFF00) + lane4)) * v3.x;
            }
            for (; i < b; ++i) {
                float2 v = slist[i];
                acc0 += *(const float*)(xqb + ((__float_as_int(v.y) & 0x3FFF00) + lane4)) * v.x;
            }
            sxk[(r - rbase) * XSTR + lane] = (acc0 + acc1) + (acc2 + acc3);
        }
        __syncthreads();
        // ---- partial einsum over this phase's k range
        if (lane < 32) {
            const int kbase = ph ? 5 : 0;
            const int kcnt  = ph ? 4 : 5;
            for (int kk = 0; kk < kcnt; ++kk) {
                const float* xr = &sxk[(kk * 16 + nl) * XSTR + h * 32];
                const float* wp = &wT[((kbase + kk) * 8 + wv) * 128];   // uniform -> s_load
#pragma unroll
                for (int c4 = 0; c4 < 8; ++c4) {
                    float4 xv = *(const float4*)&xr[c4 * 4];
#pragma unroll
                    for (int cc = 0; cc < 4; ++cc) {
                        float xval = (&xv.x)[cc];
#pragma unroll
                        for (int j = 0; j < 4; ++j)
                            acc[j] += xval * wp[(c4 * 4 + cc) * 4 + j];
                    }
                }
            }
        }
        __syncthreads();
    }

    if (lane < 32) {
        const int n0 = bkt * 16;
#pragma unroll
        for (int j = 0; j < 4; ++j) {
            int o = wv * 4 + j;
            out[((size_t)h * COUT + o) * N_OUT + n0 + nl] = acc[j] + bias[o];
        }
    }
}

// ---------------------------------------------------------------------------
extern "C" void kernel_launch(void* const* d_in, const int* in_sizes, int n_in,
                              void* d_out, int out_size, void* d_ws, size_t ws_size,
                              hipStream_t stream) {
    const float* x    = (const float*)d_in[0];
    const float* qw   = (const float*)d_in[1];
    const float* vals = (const float*)d_in[2];
    const float* w    = (const float*)d_in[3];
    const float* bias = (const float*)d_in[4];
    const int*   ik   = (const int*)d_in[5];
    const int*   io   = (const int*)d_in[6];
    const int*   ii   = (const int*)d_in[7];
    const int    nnz  = in_sizes[2];
    const int    nchA = (nnz + CHA - 1) / CHA;

    char* ws = (char*)d_ws;
    float*  xq    = (float*)ws;  ws += (size_t)N_IN * BC * 4;        // 4 MB
    float2* sivA  = (float2*)ws; ws += (size_t)64 * ECAP_A * 8;      // 16.78 MB
    float2* sivB  = (float2*)ws; ws += (size_t)1024 * ECAP_B * 8;    // 16.78 MB
    int*    gcntA = (int*)ws;    ws += 64 * 4;
    int*    gcntB = (int*)ws;    ws += 1024 * 4;
    float*  wT    = (float*)ws;  ws += (size_t)COUT * CIN * KSZ * 4;

    k_xq    <<<257, 256, 0, stream>>>(x, qw, xq, w, wT, gcntA, gcntB);
    k_binA  <<<nchA, 512, 0, stream>>>(vals, ik, io, ii, gcntA, sivA, nnz);
    k_binB  <<<256, 512, 0, stream>>>(sivA, gcntA, gcntB, sivB);
    k_fused5<<<1024, 512, 0, stream>>>(xq, sivB, gcntB, wT, bias, (float*)d_out);
}

// Round 11
// 148.916 us; speedup vs baseline: 1.2231x; 1.0510x over previous
//
#include <hip/hip_runtime.h>

#define N_IN   16384
#define N_OUT  16384
#define KSZ    9
#define CIN    32
#define COUT   32
#define BC     64
#define NCB    256         // coarse buckets = io >> 6  (64 n each)
#define CHA    4096        // bin chunk
#define ECAP_A 8192        // sivA region per coarse bucket (mean 5859, +30 sigma)
#define ROWS   144         // 9 k * 16 n per fine slice
#define XSTR   68          // sxk row stride: %32==4 -> max 4-way on b128, 16B-aligned
#define SCAP   2048        // slist cap per fine slice (mean 1465)

// ---------------------------------------------------------------------------
// blocks 0..255: xq[in][bc] = x[bc][in]*qw[in]; block 256: wT transpose + cnt zero
__global__ void k_xq(const float* __restrict__ x, const float* __restrict__ qw,
                     float* __restrict__ xq, const float* __restrict__ w,
                     float* __restrict__ wT, int* __restrict__ gcntA) {
    const int tid = threadIdx.x;
    if (blockIdx.x == 256) {
        for (int i = tid; i < COUT * CIN * KSZ; i += 256) {
            int o = i / (CIN * KSZ);
            int r = i - o * (CIN * KSZ);
            int c = r / KSZ;
            int k = r - c * KSZ;
            wT[((k * 8 + (o >> 2)) * 32 + c) * 4 + (o & 3)] = w[i];
        }
        if (tid < NCB) gcntA[tid] = 0;
        return;
    }
    __shared__ float tile[64 * 65];
    const int in0 = blockIdx.x * 64;
#pragma unroll
    for (int i = 0; i < 16; ++i) {
        int idx = tid + i * 256;
        int bcl = idx >> 6, inl = idx & 63;
        tile[bcl * 65 + inl] = x[bcl * N_IN + in0 + inl];
    }
    __syncthreads();
#pragma unroll
    for (int i = 0; i < 16; ++i) {
        int idx = tid + i * 256;
        int inl = idx >> 6, bcl = idx & 63;
        xq[(size_t)(in0 + inl) * BC + bcl] = tile[bcl * 65 + inl] * qw[in0 + inl];
    }
}

// ---------------------------------------------------------------------------
// single-pass binning into 256 coarse buckets. Runs ~16 entries = 128 B.
// payload = (io>>4)<<22 | in<<8 | row ; row = k*16 + (io&15).
__global__ __launch_bounds__(512) void k_binA(const float* __restrict__ vals,
        const int* __restrict__ ik, const int* __restrict__ io, const int* __restrict__ ii,
        int* __restrict__ gcntA, float2* __restrict__ sivA, int nnz) {
    __shared__ int    cnt[NCB], cntE[NCB], gbase[NCB], cursor[NCB];
    __shared__ float2 slist[CHA];    // 32 KB
    const int t = threadIdx.x, c = blockIdx.x;
    if (t < NCB) cnt[t] = 0;
    __syncthreads();
    const int base = c * CHA;
    const int e0   = base + t * 8;

    float vv[8]; int pk[8]; int bk[8]; bool hv[8];
    if (e0 + 8 <= nnz) {
        int4 a0 = *(const int4*)(io + e0),  a1 = *(const int4*)(io + e0 + 4);
        int4 b0 = *(const int4*)(ii + e0),  b1 = *(const int4*)(ii + e0 + 4);
        int4 k0 = *(const int4*)(ik + e0),  k1 = *(const int4*)(ik + e0 + 4);
        float4 d0 = *(const float4*)(vals + e0), d1 = *(const float4*)(vals + e0 + 4);
        int ov[8] = {a0.x, a0.y, a0.z, a0.w, a1.x, a1.y, a1.z, a1.w};
        int iv[8] = {b0.x, b0.y, b0.z, b0.w, b1.x, b1.y, b1.z, b1.w};
        int kv[8] = {k0.x, k0.y, k0.z, k0.w, k1.x, k1.y, k1.z, k1.w};
        float dv[8] = {d0.x, d0.y, d0.z, d0.w, d1.x, d1.y, d1.z, d1.w};
#pragma unroll
        for (int j = 0; j < 8; ++j) {
            hv[j] = true;
            bk[j] = ov[j] >> 6;
            pk[j] = (int)(((unsigned)(ov[j] >> 4) << 22)) | (iv[j] << 8) | (kv[j] * 16 + (ov[j] & 15));
            vv[j] = dv[j];
        }
    } else {
#pragma unroll
        for (int j = 0; j < 8; ++j) {
            int e = e0 + j;
            hv[j] = (e < nnz);
            if (hv[j]) {
                int o = io[e];
                bk[j] = o >> 6;
                pk[j] = (int)(((unsigned)(o >> 4) << 22)) | (ii[e] << 8) | (ik[e] * 16 + (o & 15));
                vv[j] = vals[e];
            } else { bk[j] = 0; pk[j] = 0; vv[j] = 0.f; }
        }
    }
#pragma unroll
    for (int j = 0; j < 8; ++j) if (hv[j]) atomicAdd(&cnt[bk[j]], 1);
    __syncthreads();
    // ---- reserve (t<256) then wave-0 exclusive scan over 256 counts
    if (t < NCB) {
        int cv = cnt[t];
        gbase[t] = t * ECAP_A + (cv ? atomicAdd(&gcntA[t], cv) : 0);
    }
    if (t < 64) {
        int carry = 0;
#pragma unroll
        for (int seg = 0; seg < 4; ++seg) {
            int idx = seg * 64 + t;
            int v = cnt[idx];
            int orig = v;
#pragma unroll
            for (int off = 1; off < 64; off <<= 1) {
                int u = __shfl_up(v, off);
                if (t >= off) v += u;
            }
            cntE[idx]   = carry + v - orig;
            cursor[idx] = carry + v - orig;
            carry += __shfl(v, 63);
        }
    }
    __syncthreads();
#pragma unroll
    for (int j = 0; j < 8; ++j) {
        if (hv[j]) {
            int pos = atomicAdd(&cursor[bk[j]], 1);
            slist[pos] = make_float2(vv[j], __int_as_float(pk[j]));
        }
    }
    __syncthreads();
    // ---- coalesced flush: consecutive p -> consecutive dest within runs
    const int m = min(nnz - base, CHA);
    for (int p = t; p < m; p += 512) {
        float2 f = slist[p];
        int cb = (int)((unsigned)__float_as_int(f.y) >> 24);  // fine>>2
        int dest = gbase[cb] + (p - cntE[cb]);
        if (dest < (cb + 1) * ECAP_A) sivA[dest] = f;
    }
}

// ---------------------------------------------------------------------------
// fused: block = fine slice f (16 n). Streams coarse bucket f>>2, filters its
// quarter into LDS scratch (aliased on sxk), row-sorts, accumulates, einsum.
__global__ __launch_bounds__(512) void k_fused6(const float* __restrict__ xq,
        const float2* __restrict__ sivA, const int* __restrict__ gcntA,
        const float* __restrict__ wT, const float* __restrict__ bias,
        float* __restrict__ out) {
    __shared__ __align__(16) float sxk[80 * XSTR];   // 21760 B (>= SCAP*8 for tmp)
    __shared__ float2 slist[SCAP];                   // 16384 B
    __shared__ int    rowStart[ROWS + 1];
    __shared__ int    cursor[ROWS];
    __shared__ int    mcur;
    const int tid  = threadIdx.x;
    const int lane = tid & 63;
    const int wv   = __builtin_amdgcn_readfirstlane(tid >> 6);
    const unsigned f = blockIdx.x;

    if (tid < ROWS) rowStart[tid] = 0;
    if (tid == 0) mcur = 0;
    __syncthreads();

    // ---- filter pass: coarse bucket -> unsorted tmp (aliased on sxk) + row counts
    const int cb = (int)(f >> 2);
    const int mA = min(gcntA[cb], ECAP_A);
    const float2* src = sivA + (size_t)cb * ECAP_A;
    float2* tmp = (float2*)sxk;
    for (int i = tid; i < mA; i += 512) {
        float2 v = src[i];
        unsigned fid = (unsigned)__float_as_int(v.y) >> 22;
        if (fid == f) {
            int pos = atomicAdd(&mcur, 1);
            if (pos < SCAP) {
                tmp[pos] = v;
                atomicAdd(&rowStart[__float_as_int(v.y) & 0xFF], 1);
            }
        }
    }
    __syncthreads();
    const int m2 = min(mcur, SCAP);
    // ---- wave-0 exclusive scan over 144 counts
    if (wv == 0) {
        int carry = 0;
#pragma unroll
        for (int i0 = 0; i0 < 192; i0 += 64) {
            int idx = i0 + lane;
            int v = (idx < ROWS) ? rowStart[idx] : 0;
            int orig = v;
#pragma unroll
            for (int off = 1; off < 64; off <<= 1) {
                int u = __shfl_up(v, off);
                if (lane >= off) v += u;
            }
            if (idx < ROWS) {
                int excl = carry + v - orig;
                rowStart[idx] = excl;
                cursor[idx]   = excl;
            }
            carry += __shfl(v, 63);
        }
        if (lane == 0) rowStart[ROWS] = carry;
    }
    __syncthreads();
    // ---- LDS->LDS scatter into row-sorted slist
    for (int i = tid; i < m2; i += 512) {
        float2 v = tmp[i];
        int pos = atomicAdd(&cursor[__float_as_int(v.y) & 0xFF], 1);
        slist[pos] = v;
    }
    __syncthreads();   // tmp reads complete before sxk is zeroed

    const char* xqb   = (const char*)xq;
    const int   lane4 = lane * 4;
    const int   h     = lane >> 4;
    const int   nl    = lane & 15;
    float acc[4] = {0.f, 0.f, 0.f, 0.f};

#pragma unroll
    for (int ph = 0; ph < 2; ++ph) {
        const int rbase = ph ? 80 : 0;
        const int rend  = ph ? 144 : 80;
        const int nrows = rend - rbase;
        for (int i = tid; i < nrows * XSTR; i += 512) sxk[i] = 0.f;
        __syncthreads();
        // ---- per-wave row accumulation: 32-bit byte-offset gathers, 8-deep
        for (int r = rbase + wv; r < rend; r += 8) {
            const int a = rowStart[r], b = rowStart[r + 1];
            if (a >= b) continue;
            float acc0 = 0.f, acc1 = 0.f, acc2 = 0.f, acc3 = 0.f;
            int i = a;
            for (; i + 7 < b; i += 8) {
                float2 v0 = slist[i],     v1 = slist[i + 1], v2 = slist[i + 2], v3 = slist[i + 3];
                float2 v4 = slist[i + 4], v5 = slist[i + 5], v6 = slist[i + 6], v7 = slist[i + 7];
                acc0 += *(const float*)(xqb + ((__float_as_int(v0.y) & 0x3FFF00) + lane4)) * v0.x;
                acc1 += *(const float*)(xqb + ((__float_as_int(v1.y) & 0x3FFF00) + lane4)) * v1.x;
                acc2 += *(const float*)(xqb + ((__float_as_int(v2.y) & 0x3FFF00) + lane4)) * v2.x;
                acc3 += *(const float*)(xqb + ((__float_as_int(v3.y) & 0x3FFF00) + lane4)) * v3.x;
                acc0 += *(const float*)(xqb + ((__float_as_int(v4.y) & 0x3FFF00) + lane4)) * v4.x;
                acc1 += *(const float*)(xqb + ((__float_as_int(v5.y) & 0x3FFF00) + lane4)) * v5.x;
                acc2 += *(const float*)(xqb + ((__float_as_int(v6.y) & 0x3FFF00) + lane4)) * v6.x;
                acc3 += *(const float*)(xqb + ((__float_as_int(v7.y) & 0x3FFF00) + lane4)) * v7.x;
            }
            for (; i + 3 < b; i += 4) {
                float2 v0 = slist[i], v1 = slist[i + 1], v2 = slist[i + 2], v3 = slist[i + 3];
                acc0 += *(const float*)(xqb + ((__float_as_int(v0.y) & 0x3FFF00) + lane4)) * v0.x;
                acc1 += *(const float*)(xqb + ((__float_as_int(v1.y) & 0x3FFF00) + lane4)) * v1.x;
                acc2 += *(const float*)(xqb + ((__float_as_int(v2.y) & 0x3FFF00) + lane4)) * v2.x;
                acc3 += *(const float*)(xqb + ((__float_as_int(v3.y) & 0x3FFF00) + lane4)) * v3.x;
            }
            for (; i < b; ++i) {
                float2 v = slist[i];
                acc0 += *(const float*)(xqb + ((__float_as_int(v.y) & 0x3FFF00) + lane4)) * v.x;
            }
            sxk[(r - rbase) * XSTR + lane] = (acc0 + acc1) + (acc2 + acc3);
        }
        __syncthreads();
        // ---- partial einsum over this phase's k range
        if (lane < 32) {
            const int kbase = ph ? 5 : 0;
            const int kcnt  = ph ? 4 : 5;
            for (int kk = 0; kk < kcnt; ++kk) {
                const float* xr = &sxk[(kk * 16 + nl) * XSTR + h * 32];
                const float* wp = &wT[((kbase + kk) * 8 + wv) * 128];   // uniform -> s_load
#pragma unroll
                for (int c4 = 0; c4 < 8; ++c4) {
                    float4 xv = *(const float4*)&xr[c4 * 4];
#pragma unroll
                    for (int cc = 0; cc < 4; ++cc) {
                        float xval = (&xv.x)[cc];
#pragma unroll
                        for (int j = 0; j < 4; ++j)
                            acc[j] += xval * wp[(c4 * 4 + cc) * 4 + j];
                    }
                }
            }
        }
        __syncthreads();
    }

    if (lane < 32) {
        const int n0 = (int)f * 16;
#pragma unroll
        for (int j = 0; j < 4; ++j) {
            int o = wv * 4 + j;
            out[((size_t)h * COUT + o) * N_OUT + n0 + nl] = acc[j] + bias[o];
        }
    }
}

// ---------------------------------------------------------------------------
extern "C" void kernel_launch(void* const* d_in, const int* in_sizes, int n_in,
                              void* d_out, int out_size, void* d_ws, size_t ws_size,
                              hipStream_t stream) {
    const float* x    = (const float*)d_in[0];
    const float* qw   = (const float*)d_in[1];
    const float* vals = (const float*)d_in[2];
    const float* w    = (const float*)d_in[3];
    const float* bias = (const float*)d_in[4];
    const int*   ik   = (const int*)d_in[5];
    const int*   io   = (const int*)d_in[6];
    const int*   ii   = (const int*)d_in[7];
    const int    nnz  = in_sizes[2];
    const int    nchA = (nnz + CHA - 1) / CHA;

    char* ws = (char*)d_ws;
    float*  xq    = (float*)ws;  ws += (size_t)N_IN * BC * 4;        // 4 MB
    float2* sivA  = (float2*)ws; ws += (size_t)NCB * ECAP_A * 8;     // 16.78 MB
    int*    gcntA = (int*)ws;    ws += NCB * 4;
    float*  wT    = (float*)ws;  ws += (size_t)COUT * CIN * KSZ * 4;

    k_xq    <<<257, 256, 0, stream>>>(x, qw, xq, w, wT, gcntA);
    k_binA  <<<nchA, 512, 0, stream>>>(vals, ik, io, ii, gcntA, sivA, nnz);
    k_fused6<<<1024, 512, 0, stream>>>(xq, sivA, gcntA, wT, bias, (float*)d_out);
}